// Round 8
// baseline (227.168 us; speedup 1.0000x reference)
//
#include <hip/hip_runtime.h>

// SelfAttention (B=4, T=1024, C=1024, H=16, HD=64). fp32 in / fp32 out.
// R17: balanced flash grid. Static-max softmax (R16) makes O/denom pure
//      sums over j -> heavy i-tiles (it>=8, rows i>=512) split into two
//      j-chunk blocks that atomicAdd fp32 partials (y32 in dead x16 plane,
//      den in dead WaT region); it<=7 keep the direct y16 path. Grid
//      (64,24), size-descending dispatch (max block 8 tiles vs 17; 1536
//      blocks > 1024 slots -> refill). zero_ws after qkv; norm_y before
//      proj divides+converts rows>=512.
// Flash tile body unchanged from R16 (40KB LDS, gload_lds staging w/
// inverse-swizzled source, 3 barriers, setprio). Lessons: no min-waves
// clause (R11), no reg prefetch (R13), keep residency (R14).
// ws (50 MiB): q(0) k(1) vT(2) y16(3) x16/y32(4) WaT/den WpT E16.

typedef __bf16 bf16x8 __attribute__((ext_vector_type(8)));
typedef float f32x4 __attribute__((ext_vector_type(4)));
typedef unsigned short ushort_t;

#define T_SEQ 1024
#define NHEAD 16
#define HDIM 64
#define PLANE 4194304
#define C1SCALE 0.1803368836f   // 0.125 * log2(e)
#define SMAX 20.0f              // static softmax max (log2 domain)

__device__ __forceinline__ float bf2f(ushort_t h) {
    unsigned int u = ((unsigned int)h) << 16;
    float f; __builtin_memcpy(&f, &u, 4); return f;
}
__device__ __forceinline__ ushort_t f2bf(float f) {
    __bf16 h = (__bf16)f;
    ushort_t u; __builtin_memcpy(&u, &h, 2); return u;
}

__global__ __launch_bounds__(256) void sentinel_kernel(float* out, int n, float val) {
    const int i = blockIdx.x * 256 + threadIdx.x;
    if (i < n) out[i] = val;
}

// fused preprocessing: [0,4096) x-convert, [4096,5120) E-convert (scaled by
// c1), [5120,5888) Wa transpose (48x16), [5888,6144) Wp transpose (16x16)
__global__ __launch_bounds__(256) void prep(
    const float* __restrict__ x, ushort_t* __restrict__ x16,
    const float* __restrict__ E, ushort_t* __restrict__ E16,
    const float* __restrict__ Wa, ushort_t* __restrict__ WaT,
    const float* __restrict__ Wp, ushort_t* __restrict__ WpT)
{
    __shared__ ushort_t t[64][65];
    const int bid = blockIdx.x;
    if (bid < 5120) {   // converts, no LDS use
        const float* src; ushort_t* dst; int base; float sc;
        if (bid < 4096) { src = x; dst = x16; base = bid * 1024; sc = 1.0f; }
        else            { src = E; dst = E16; base = (bid - 4096) * 1024; sc = C1SCALE; }
        const int i = base + (int)threadIdx.x * 4;
        const float4 v = *reinterpret_cast<const float4*>(src + i);
        union { unsigned long long u; ushort_t s[4]; } o;
        o.s[0] = f2bf(v.x * sc); o.s[1] = f2bf(v.y * sc);
        o.s[2] = f2bf(v.z * sc); o.s[3] = f2bf(v.w * sc);
        *reinterpret_cast<unsigned long long*>(dst + i) = o.u;
        return;
    }
    const float* W; ushort_t* Wt; int Kdim, Ndim, n0, k0;
    if (bid < 5888) {
        const int r = bid - 5120;
        W = Wa; Wt = WaT; Kdim = 1024; Ndim = 3072;
        n0 = (r % 48) * 64; k0 = (r / 48) * 64;
    } else {
        const int r = bid - 5888;
        W = Wp; Wt = WpT; Kdim = 1024; Ndim = 1024;
        n0 = (r % 16) * 64; k0 = (r / 16) * 64;
    }
    const int cx = threadIdx.x & 63, ry = threadIdx.x >> 6;
#pragma unroll
    for (int i = 0; i < 16; i++) {
        const int r = ry + i * 4;
        t[r][cx] = f2bf(W[(size_t)(k0 + r) * Ndim + n0 + cx]);
    }
    __syncthreads();
#pragma unroll
    for (int i = 0; i < 16; i++) {
        const int r = ry + i * 4;
        Wt[(size_t)(n0 + r) * Kdim + k0 + cx] = t[cx][r];
    }
}

// zero the atomic-partial buffers (runs AFTER qkv: clobbers x16/WaT planes)
// [0,2048): y32 (2M f32), [2048,2080): den (32K f32)
__global__ __launch_bounds__(256) void zero_ws(float* __restrict__ y32,
                                               float* __restrict__ den)
{
    const int bid = blockIdx.x;
    float4* p = (bid < 2048)
        ? reinterpret_cast<float4*>(y32) + (size_t)bid * 256 + threadIdx.x
        : reinterpret_cast<float4*>(den) + (size_t)(bid - 2048) * 256 + threadIdx.x;
    *p = (float4){0.f, 0.f, 0.f, 0.f};
}

// normalize rows i>=512: y16 = f2bf(y32 / den). one row (b, i_rel) per block.
__global__ __launch_bounds__(256) void norm_y(const float* __restrict__ y32,
                                              const float* __restrict__ den,
                                              ushort_t* __restrict__ y16)
{
    const int bid = blockIdx.x;             // 2048 rows (4 b x 512)
    const int b = bid >> 9, irel = bid & 511;
    const float4 v = reinterpret_cast<const float4*>(y32 + (size_t)bid * 1024)[threadIdx.x];
    const float inv = 1.0f / den[(size_t)bid * 16 + (threadIdx.x >> 4)];
    union { unsigned long long u; ushort_t s[4]; } o;
    o.s[0] = f2bf(v.x * inv); o.s[1] = f2bf(v.y * inv);
    o.s[2] = f2bf(v.z * inv); o.s[3] = f2bf(v.w * inv);
    reinterpret_cast<unsigned long long*>(
        y16 + ((size_t)(b * T_SEQ + 512 + irel)) * 1024)[threadIdx.x] = o.u;
}

// ---------------------------------------------------------------------------
// m97-style MFMA GEMM (unchanged from R16).
// ---------------------------------------------------------------------------
template <int MODE, int BN>
__global__ __launch_bounds__(256) void gemm128(
    const ushort_t* __restrict__ A16, const ushort_t* __restrict__ Bt,
    const float* __restrict__ bias, void* __restrict__ out_,
    int Ndim, int Kdim)
{
    constexpr int NT = BN / 32;   // n-frags per wave (4 or 2)
    __shared__ __align__(16) ushort_t As[128 * 32];
    __shared__ __align__(16) ushort_t Bs[BN * 32];

    const int tid = threadIdx.x;
    const int w = tid >> 6;
    const int lane = tid & 63;
    const int l15 = lane & 15;
    const int quad = lane >> 4;
    const int m0 = blockIdx.y * 128, n0 = blockIdx.x * BN;
    const int wm = (w & 1) * 64, wn = (w >> 1) * (BN / 2);

    f32x4 acc[4][NT];
#pragma unroll
    for (int mt = 0; mt < 4; mt++)
#pragma unroll
        for (int nt = 0; nt < NT; nt++) acc[mt][nt] = (f32x4){0.f, 0.f, 0.f, 0.f};

    for (int kk = 0; kk < Kdim; kk += 32) {
        __syncthreads();
#pragma unroll
        for (int t = 0; t < 2; t++) {
            const int chunk = w * 128 + t * 64 + lane;
            const int row = chunk >> 2, kc = (chunk & 3) * 8;
            __builtin_amdgcn_global_load_lds(
                (const __attribute__((address_space(1))) void*)
                    (A16 + (size_t)(m0 + row) * Kdim + kk + kc),
                (__attribute__((address_space(3))) void*)
                    (As + (size_t)(w * 128 + t * 64) * 8), 16, 0, 0);
            if (BN == 128)
                __builtin_amdgcn_global_load_lds(
                    (const __attribute__((address_space(1))) void*)
                        (Bt + (size_t)(n0 + row) * Kdim + kk + kc),
                    (__attribute__((address_space(3))) void*)
                        (Bs + (size_t)(w * 128 + t * 64) * 8), 16, 0, 0);
        }
        if (BN == 64) {
            const int chunk = w * 64 + lane;
            const int row = chunk >> 2, kc = (chunk & 3) * 8;
            __builtin_amdgcn_global_load_lds(
                (const __attribute__((address_space(1))) void*)
                    (Bt + (size_t)(n0 + row) * Kdim + kk + kc),
                (__attribute__((address_space(3))) void*)
                    (Bs + (size_t)(w * 64) * 8), 16, 0, 0);
        }
        __syncthreads();

        bf16x8 af[4], bf[NT];
#pragma unroll
        for (int mt = 0; mt < 4; mt++)
            af[mt] = *reinterpret_cast<const bf16x8*>(&As[(wm + mt * 16 + l15) * 32 + quad * 8]);
#pragma unroll
        for (int nt = 0; nt < NT; nt++)
            bf[nt] = *reinterpret_cast<const bf16x8*>(&Bs[(wn + nt * 16 + l15) * 32 + quad * 8]);
#pragma unroll
        for (int mt = 0; mt < 4; mt++)
#pragma unroll
            for (int nt = 0; nt < NT; nt++)
                acc[mt][nt] = __builtin_amdgcn_mfma_f32_16x16x32_bf16(
                    af[mt], bf[nt], acc[mt][nt], 0, 0, 0);
    }

#pragma unroll
    for (int mt = 0; mt < 4; mt++)
#pragma unroll
        for (int nt = 0; nt < NT; nt++) {
            const int n = n0 + wn + nt * 16 + l15;
            const float bv = bias[n];
#pragma unroll
            for (int r = 0; r < 4; r++) {
                const int m = m0 + wm + mt * 16 + quad * 4 + r;
                const float val = acc[mt][nt][r] + bv;
                if (MODE == 0) {
                    ushort_t* ws = (ushort_t*)out_;
                    const int which = n >> 10;         // 0:q 1:k 2:v
                    const int cc = n & 1023;
                    const int h = cc >> 6, d = cc & 63;
                    const int bb = m >> 10, t = m & 1023;
                    if (which == 2) {
                        ws[2 * PLANE + ((size_t)(bb * NHEAD + h) * HDIM + d) * T_SEQ + t] = f2bf(val);
                    } else {
                        const float sv = (which == 0) ? val * C1SCALE : val;
                        ws[(size_t)which * PLANE +
                           ((size_t)(bb * NHEAD + h) * T_SEQ + t) * HDIM + d] = f2bf(sv);
                    }
                } else {
                    ((float*)out_)[(size_t)m * Ndim + n] = val;
                }
            }
        }
}

// ---------------------------------------------------------------------------
// Flash attention w/ rel-pos band. Grid (64, 24): bh = bx; by indexes a
// size-descending dispatch table of (i-tile, j-chunk):
//   it >= 8: two chunks (j-halves, ceil first) -> fp32 atomic partials
//   it <= 7: full j-range -> direct y16 write (divide by own denominator)
// Tile body identical to R16 (40KB LDS, gload_lds staging w/ inverse-
// swizzled source, swizzled Ks/Vt/Es/Ps, static-max softmax, 3 barriers).
// ---------------------------------------------------------------------------
__global__ __launch_bounds__(256) void flash_attn(
    const ushort_t* __restrict__ qp, const ushort_t* __restrict__ kp,
    const ushort_t* __restrict__ vTp, const ushort_t* __restrict__ E16,
    ushort_t* __restrict__ y16, float* __restrict__ y32,
    float* __restrict__ den)
{
    __shared__ __align__(16) ushort_t Ks[64 * 64];    // K tile; probs after S3
    __shared__ __align__(16) ushort_t Vt[64 * 64];
    __shared__ __align__(16) ushort_t Es[128 * 64];   // E band
    __shared__ __align__(16) ushort_t Ps[64 * 64];    // skewed P band

    // size-descending (it, chunk) table: hf 0 = first j-half, 1 = second,
    // 2 = full range (no split)
    static const signed char TBL_IT[24] =
        {15,15,14, 7,14,13,13,12, 6,12,11,11,10, 5,10, 9, 9, 8, 4, 8, 3, 2, 1, 0};
    static const signed char TBL_HF[24] =
        { 0, 1, 0, 2, 1, 0, 1, 0, 2, 1, 0, 1, 0, 2, 1, 0, 1, 0, 2, 1, 2, 2, 2, 2};

    const int bh = blockIdx.x;
    const int h = bh & (NHEAD - 1);
    const int b = bh >> 4;
    const int by = blockIdx.y;
    const int it = TBL_IT[by];
    const int hf = TBL_HF[by];
    const int ntile = it + 1;
    const int jb = (hf == 1) ? ((it + 2) >> 1) : 0;
    const int je = (hf == 0) ? ((it + 2) >> 1) : ntile;

    const int tid = threadIdx.x;
    const int w = tid >> 6;
    const int lane = tid & 63;
    const int l15 = lane & 15;
    const int quad = lane >> 4;

    const size_t base = (size_t)bh * T_SEQ * HDIM;
    const ushort_t* Eh = E16 + (size_t)h * T_SEQ * HDIM;
    const ushort_t* vTb = vTp + (size_t)bh * 65536;

    const int kswz = (l15 & 7) << 3;   // read-side col XOR (row ≡ l15 mod 8)
    const int jswz = quad << 4;        // Ps gather XOR ((il>>2)&3 == quad)

    // staging lane geometry (per 8-row global_load_lds call)
    const int srow = lane >> 3;        // row within 8-row block
    const int scc  = lane & 7;         // 16B chunk within 128B row

    bf16x8 ones;
#pragma unroll
    for (int i = 0; i < 8; i++) ones[i] = (__bf16)1.0f;

    const int i0 = it * 64;

    // Q A-fragments straight from global (wave-private rows; pre-scaled c1)
    bf16x8 qf[2];
    {
        const ushort_t* qrow = qp + base + (size_t)(i0 + w * 16 + l15) * HDIM;
        qf[0] = *reinterpret_cast<const bf16x8*>(qrow + quad * 8);
        qf[1] = *reinterpret_cast<const bf16x8*>(qrow + 32 + quad * 8);
    }

    f32x4 o[4], o5;
#pragma unroll
    for (int dt = 0; dt < 4; dt++) o[dt] = (f32x4){0.f, 0.f, 0.f, 0.f};
    o5 = (f32x4){0.f, 0.f, 0.f, 0.f};

    for (int jt = jb; jt < je; ++jt) {
        const int j0 = jt * 64;
        const int d0 = i0 - j0;
        __syncthreads();   // S1: prev tile's PV reads done (Ks/Vt/Es free)
        {   // stage K, V^T, E via global_load_lds (zero VGPR)
#pragma unroll
            for (int t = 0; t < 2; t++) {
                const int r0 = w * 16 + t * 8;
                const int row = r0 + srow;
                const int sx = (scc ^ (row & 7)) << 3;   // src chunk element offset
                __builtin_amdgcn_global_load_lds(
                    (const __attribute__((address_space(1))) void*)
                        (kp + base + (size_t)(j0 + row) * HDIM + sx),
                    (__attribute__((address_space(3))) void*)(&Ks[r0 * 64]),
                    16, 0, 0);
                __builtin_amdgcn_global_load_lds(
                    (const __attribute__((address_space(1))) void*)
                        (vTb + (size_t)row * T_SEQ + j0 + sx),
                    (__attribute__((address_space(3))) void*)(&Vt[r0 * 64]),
                    16, 0, 0);
            }
#pragma unroll
            for (int t = 0; t < 4; t++) {
                const int r0 = w * 32 + t * 8;
                const int row = r0 + srow;
                int g = d0 - 64 + row;
                g = g < 0 ? 0 : (g > 1023 ? 1023 : g);
                const int sx = (scc ^ (row & 7)) << 3;
                __builtin_amdgcn_global_load_lds(
                    (const __attribute__((address_space(1))) void*)
                        (Eh + (size_t)g * HDIM + sx),
                    (__attribute__((address_space(3))) void*)(&Es[r0 * 64]),
                    16, 0, 0);
            }
        }
        __syncthreads();   // S2: staging complete (drains vmcnt + lgkmcnt)

        // ---- phase 1: S = Q@K^T ; P band = E@K^T (both pre-scaled c1) ----
        f32x4 s[4], pb[2][4];
#pragma unroll
        for (int nt = 0; nt < 4; nt++) {
            s[nt] = (f32x4){0.f, 0.f, 0.f, 0.f};
            pb[0][nt] = (f32x4){0.f, 0.f, 0.f, 0.f};
            pb[1][nt] = (f32x4){0.f, 0.f, 0.f, 0.f};
        }
        __builtin_amdgcn_s_setprio(1);
#pragma unroll
        for (int ks = 0; ks < 2; ks++) {
            const int ko = ks * 32 + quad * 8;
            const bf16x8 ae0 = *reinterpret_cast<const bf16x8*>(&Es[(w * 32 + l15) * 64 + (ko ^ kswz)]);
            const bf16x8 ae1 = *reinterpret_cast<const bf16x8*>(&Es[(w * 32 + 16 + l15) * 64 + (ko ^ kswz)]);
#pragma unroll
            for (int nt = 0; nt < 4; nt++) {
                const bf16x8 bk = *reinterpret_cast<const bf16x8*>(&Ks[(nt * 16 + l15) * 64 + (ko ^ kswz)]);
                s[nt] = __builtin_amdgcn_mfma_f32_16x16x32_bf16(qf[ks], bk, s[nt], 0, 0, 0);
                pb[0][nt] = __builtin_amdgcn_mfma_f32_16x16x32_bf16(ae0, bk, pb[0][nt], 0, 0, 0);
                pb[1][nt] = __builtin_amdgcn_mfma_f32_16x16x32_bf16(ae1, bk, pb[1][nt], 0, 0, 0);
            }
        }
        __builtin_amdgcn_s_setprio(0);
        // skewed store: Ps[il][jl] = P[il-jl+64][jl]; OOB lanes just skip
#pragma unroll
        for (int mf = 0; mf < 2; mf++)
#pragma unroll
            for (int nt = 0; nt < 4; nt++) {
                const int jl = nt * 16 + l15;
#pragma unroll
                for (int r = 0; r < 4; r++) {
                    const int br = w * 32 + mf * 16 + quad * 4 + r;
                    const int il_t = br - 64 + jl;
                    if ((unsigned)il_t < 64u)
                        Ps[il_t * 64 + (jl ^ (((il_t >> 2) & 3) << 4))] = f2bf(pb[mf][nt][r]);
                }
            }
        __syncthreads();   // S3 (also: all Ks reads drained -> Ks reusable)

        // ---- gather (own slot) + static-max softmax: P = exp2(sv - SMAX) ----
        float pv[4][4];
        const int il0 = w * 16 + quad * 4;
        if (j0 < i0) {       // interior: no mask
#pragma unroll
            for (int nt = 0; nt < 4; nt++) {
                const int jl = nt * 16 + l15;
#pragma unroll
                for (int r = 0; r < 4; r++) {
                    const float sv = s[nt][r] + bf2f(Ps[(il0 + r) * 64 + (jl ^ jswz)]);
                    pv[nt][r] = exp2f(sv - SMAX);
                }
            }
        } else {             // diagonal: causal mask
#pragma unroll
            for (int nt = 0; nt < 4; nt++) {
                const int jl = nt * 16 + l15;
#pragma unroll
                for (int r = 0; r < 4; r++) {
                    const int il = il0 + r;
                    float sv = s[nt][r] + bf2f(Ps[il * 64 + (jl ^ jswz)]);
                    if (jl > il) sv = -3e38f;
                    pv[nt][r] = exp2f(sv - SMAX);
                }
            }
        }
        // probs -> Ks region (free after S3; stripe-private rows w*16..w*16+15)
#pragma unroll
        for (int nt = 0; nt < 4; nt++)
#pragma unroll
            for (int r = 0; r < 4; r++) {
                const int rr = w * 16 + quad * 4 + r;
                Ks[rr * 64 + ((nt * 16 + l15) ^ ((rr & 7) << 3))] = f2bf(pv[nt][r]);
            }
        // (no barrier: PV reads below touch only this wave's stripe)

        // ---- O += P @ V ; denominator via ones column ----
        __builtin_amdgcn_s_setprio(1);
#pragma unroll
        for (int ks = 0; ks < 2; ks++) {
            const int ko = ks * 32 + quad * 8;
            const bf16x8 ap = *reinterpret_cast<const bf16x8*>(&Ks[(w * 16 + l15) * 64 + (ko ^ kswz)]);
#pragma unroll
            for (int dt = 0; dt < 4; dt++) {
                const bf16x8 bv = *reinterpret_cast<const bf16x8*>(&Vt[(dt * 16 + l15) * 64 + (ko ^ kswz)]);
                o[dt] = __builtin_amdgcn_mfma_f32_16x16x32_bf16(ap, bv, o[dt], 0, 0, 0);
            }
            o5 = __builtin_amdgcn_mfma_f32_16x16x32_bf16(ap, ones, o5, 0, 0, 0);
        }
        __builtin_amdgcn_s_setprio(0);
    }

    // ---- epilogue ----
    if (hf == 2) {
        // full row range done: normalize locally, direct y16 write
        float inv[4];
#pragma unroll
        for (int r = 0; r < 4; r++) inv[r] = 1.0f / o5[r];
#pragma unroll
        for (int dt = 0; dt < 4; dt++)
#pragma unroll
            for (int r = 0; r < 4; r++) {
                const int il = w * 16 + quad * 4 + r;
                const int d = dt * 16 + l15;
                y16[((size_t)(b * T_SEQ + i0 + il)) * 1024 + h * 64 + d] =
                    f2bf(o[dt][r] * inv[r]);
            }
    } else {
        // partial j-chunk (it>=8 -> i0>=512): accumulate fp32 partials
        const int rb = b * 512 + (i0 - 512);
#pragma unroll
        for (int dt = 0; dt < 4; dt++)
#pragma unroll
            for (int r = 0; r < 4; r++) {
                const int il = w * 16 + quad * 4 + r;
                const int d = dt * 16 + l15;
                atomicAdd(&y32[((size_t)(rb + il)) * 1024 + h * 64 + d], o[dt][r]);
            }
        if (l15 == 0) {
#pragma unroll
            for (int r = 0; r < 4; r++) {
                const int il = w * 16 + quad * 4 + r;
                atomicAdd(&den[(size_t)(rb + il) * 16 + h], o5[r]);
            }
        }
    }
}

extern "C" void kernel_launch(void* const* d_in, const int* in_sizes, int n_in,
                              void* d_out, int out_size, void* d_ws, size_t ws_size,
                              hipStream_t stream) {
    float* out = (float*)d_out;

    const void* x = nullptr; const void* Wa = nullptr; const void* ba = nullptr;
    const void* Wp = nullptr; const void* bp = nullptr; const void* E = nullptr;
    int anomaly = 0;
    if (n_in != 6) {
        anomaly = 2;
    } else {
        int c1M = 0;
        for (int i = 0; i < 6; i++) {
            const int s = in_sizes[i];
            if      (s == 4194304) x  = d_in[i];
            else if (s == 3145728) Wa = d_in[i];
            else if (s == 3072)    ba = d_in[i];
            else if (s == 1024)    bp = d_in[i];
            else if (s == 1048576) { if (c1M == 0) Wp = d_in[i]; else E = d_in[i]; c1M++; }
            else anomaly = 1;
        }
        if (!x || !Wa || !ba || !Wp || !bp || !E || c1M != 2) anomaly = 1;
    }
    if (!anomaly && out_size != 4194304) anomaly = 3;
    if (!anomaly && ws_size < (size_t)52428800) anomaly = 4;   // 50 MiB
    if (anomaly) {
        sentinel_kernel<<<(out_size + 255) / 256, 256, 0, stream>>>(out, out_size, 1000.0f * anomaly);
        return;
    }

    ushort_t* ws   = (ushort_t*)d_ws;
    ushort_t* qp   = ws;                        // (B,H,T,HD) scaled by c1
    ushort_t* kp   = ws + (size_t)PLANE;        // (B,H,T,HD)
    ushort_t* vTp  = ws + (size_t)2 * PLANE;    // (B,H,HD,T) direct from gemm
    ushort_t* y16  = ws + (size_t)3 * PLANE;    // (B,T,C)
    ushort_t* x16  = ws + (size_t)4 * PLANE;    // x bf16; reused as y32 after qkv
    ushort_t* WaT  = ws + (size_t)5 * PLANE;    // WaT; reused as den after qkv
    ushort_t* WpT  = WaT + (size_t)3145728;
    ushort_t* E16  = WpT + (size_t)1048576;     // scaled by c1

    float* y32 = (float*)x16;                   // 2M f32 (rows i>=512), 8MB
    float* den = (float*)WaT;                   // 32K f32, 128KB

    // fused converts + weight transposes
    prep<<<6144, 256, 0, stream>>>((const float*)x, x16, (const float*)E, E16,
                                   (const float*)Wa, WaT, (const float*)Wp, WpT);

    // qkv: M=4096, N=3072, K=1024 -> q (scaled) / k / vT planes
    gemm128<0, 128><<<dim3(24, 32), 256, 0, stream>>>(x16, WaT, (const float*)ba, (void*)ws, 3072, 1024);

    // zero atomic-partial buffers (x16/WaT dead after qkv)
    zero_ws<<<2080, 256, 0, stream>>>(y32, den);

    // balanced grid (64 bh, 24 chunks), size-descending dispatch
    flash_attn<<<dim3(64, 24), 256, 0, stream>>>(qp, kp, vTp, E16, y16, y32, den);

    // normalize + convert rows i>=512
    norm_y<<<2048, 256, 0, stream>>>(y32, den, y16);

    // proj: M=4096, N=1024, K=1024 -> fp32 out (128x64 tiles, 512 blocks)
    gemm128<1, 64><<<dim3(16, 32), 256, 0, stream>>>(y16, WpT, (const float*)bp, (void*)out, 1024, 1024);
}

// Round 9
// 202.760 us; speedup vs baseline: 1.1204x; 1.1204x over previous
//
#include <hip/hip_runtime.h>

// SelfAttention (B=4, T=1024, C=1024, H=16, HD=64). fp32 in / fp32 out.
// R18: revert R17's split grid (R16 grid (64,16) was already per-CU
//      balanced: CU gets by-groups {0-3},{4-7},{8-11},{12-15} ~34 tiles).
//      On the R16 base, three per-tile cost cuts in flash:
//   1. E-band rotation: tile jt+1 E rows = tile jt rows shifted -64 ->
//      stage only 64 new rows/tile (2 gloads, was 4) into parity slot;
//      read slot = (jt&1)^(w>>1).
//   2. post-S3 early E staging (slot dead after phase-1) + lgkm-only S1
//      barrier (R14-validated pattern) -> E latency hides under sm+PV.
//   3. transposed P band Ps[jl][il] w/ 4-col XOR swizzle: gather = 4x
//      ds_read_b64 (was 16x ds_read_u16); store stays 32 predicated b16.
// Keeps R16: static-max softmax (SMAX=20), c1 folded upstream, vT fused
// into qkv, 40KB LDS 4 blocks/CU, gload_lds staging w/ inverse-swizzled
// source. Lessons: no min-waves clause (R11), no reg prefetch (R13),
// keep residency (R14), don't break natural grid balance (R17).
// ws (50 MiB): q(0) k(1) vT(2) y16(3) x16(4) WaT WpT E16.

typedef __bf16 bf16x8 __attribute__((ext_vector_type(8)));
typedef float f32x4 __attribute__((ext_vector_type(4)));
typedef unsigned short ushort_t;

#define T_SEQ 1024
#define NHEAD 16
#define HDIM 64
#define PLANE 4194304
#define C1SCALE 0.1803368836f   // 0.125 * log2(e)
#define SMAX 20.0f              // static softmax max (log2 domain)

__device__ __forceinline__ float bf2f(ushort_t h) {
    unsigned int u = ((unsigned int)h) << 16;
    float f; __builtin_memcpy(&f, &u, 4); return f;
}
// native RNE convert (v_cvt_pk_bf16_f32 on gfx950)
__device__ __forceinline__ ushort_t f2bf(float f) {
    __bf16 h = (__bf16)f;
    ushort_t u; __builtin_memcpy(&u, &h, 2); return u;
}

__global__ __launch_bounds__(256) void sentinel_kernel(float* out, int n, float val) {
    const int i = blockIdx.x * 256 + threadIdx.x;
    if (i < n) out[i] = val;
}

// fused preprocessing: [0,4096) x-convert, [4096,5120) E-convert (scaled by
// c1), [5120,5888) Wa transpose (48x16), [5888,6144) Wp transpose (16x16)
__global__ __launch_bounds__(256) void prep(
    const float* __restrict__ x, ushort_t* __restrict__ x16,
    const float* __restrict__ E, ushort_t* __restrict__ E16,
    const float* __restrict__ Wa, ushort_t* __restrict__ WaT,
    const float* __restrict__ Wp, ushort_t* __restrict__ WpT)
{
    __shared__ ushort_t t[64][65];
    const int bid = blockIdx.x;
    if (bid < 5120) {   // converts, no LDS use
        const float* src; ushort_t* dst; int base; float sc;
        if (bid < 4096) { src = x; dst = x16; base = bid * 1024; sc = 1.0f; }
        else            { src = E; dst = E16; base = (bid - 4096) * 1024; sc = C1SCALE; }
        const int i = base + (int)threadIdx.x * 4;
        const float4 v = *reinterpret_cast<const float4*>(src + i);
        union { unsigned long long u; ushort_t s[4]; } o;
        o.s[0] = f2bf(v.x * sc); o.s[1] = f2bf(v.y * sc);
        o.s[2] = f2bf(v.z * sc); o.s[3] = f2bf(v.w * sc);
        *reinterpret_cast<unsigned long long*>(dst + i) = o.u;
        return;
    }
    const float* W; ushort_t* Wt; int Kdim, Ndim, n0, k0;
    if (bid < 5888) {
        const int r = bid - 5120;
        W = Wa; Wt = WaT; Kdim = 1024; Ndim = 3072;
        n0 = (r % 48) * 64; k0 = (r / 48) * 64;
    } else {
        const int r = bid - 5888;
        W = Wp; Wt = WpT; Kdim = 1024; Ndim = 1024;
        n0 = (r % 16) * 64; k0 = (r / 16) * 64;
    }
    const int cx = threadIdx.x & 63, ry = threadIdx.x >> 6;
#pragma unroll
    for (int i = 0; i < 16; i++) {
        const int r = ry + i * 4;
        t[r][cx] = f2bf(W[(size_t)(k0 + r) * Ndim + n0 + cx]);
    }
    __syncthreads();
#pragma unroll
    for (int i = 0; i < 16; i++) {
        const int r = ry + i * 4;
        Wt[(size_t)(n0 + r) * Kdim + k0 + cx] = t[cx][r];
    }
}

// ---------------------------------------------------------------------------
// m97-style MFMA GEMM (unchanged from R16).
// MODE 0: scatter to q(0, scaled by c1)/k(1)/vT(2, [bh][d][t]) bf16 planes.
// MODE 1: fp32 row-major out.
// ---------------------------------------------------------------------------
template <int MODE, int BN>
__global__ __launch_bounds__(256) void gemm128(
    const ushort_t* __restrict__ A16, const ushort_t* __restrict__ Bt,
    const float* __restrict__ bias, void* __restrict__ out_,
    int Ndim, int Kdim)
{
    constexpr int NT = BN / 32;   // n-frags per wave (4 or 2)
    __shared__ __align__(16) ushort_t As[128 * 32];
    __shared__ __align__(16) ushort_t Bs[BN * 32];

    const int tid = threadIdx.x;
    const int w = tid >> 6;
    const int lane = tid & 63;
    const int l15 = lane & 15;
    const int quad = lane >> 4;
    const int m0 = blockIdx.y * 128, n0 = blockIdx.x * BN;
    const int wm = (w & 1) * 64, wn = (w >> 1) * (BN / 2);

    f32x4 acc[4][NT];
#pragma unroll
    for (int mt = 0; mt < 4; mt++)
#pragma unroll
        for (int nt = 0; nt < NT; nt++) acc[mt][nt] = (f32x4){0.f, 0.f, 0.f, 0.f};

    for (int kk = 0; kk < Kdim; kk += 32) {
        __syncthreads();
#pragma unroll
        for (int t = 0; t < 2; t++) {
            const int chunk = w * 128 + t * 64 + lane;
            const int row = chunk >> 2, kc = (chunk & 3) * 8;
            __builtin_amdgcn_global_load_lds(
                (const __attribute__((address_space(1))) void*)
                    (A16 + (size_t)(m0 + row) * Kdim + kk + kc),
                (__attribute__((address_space(3))) void*)
                    (As + (size_t)(w * 128 + t * 64) * 8), 16, 0, 0);
            if (BN == 128)
                __builtin_amdgcn_global_load_lds(
                    (const __attribute__((address_space(1))) void*)
                        (Bt + (size_t)(n0 + row) * Kdim + kk + kc),
                    (__attribute__((address_space(3))) void*)
                        (Bs + (size_t)(w * 128 + t * 64) * 8), 16, 0, 0);
        }
        if (BN == 64) {
            const int chunk = w * 64 + lane;
            const int row = chunk >> 2, kc = (chunk & 3) * 8;
            __builtin_amdgcn_global_load_lds(
                (const __attribute__((address_space(1))) void*)
                    (Bt + (size_t)(n0 + row) * Kdim + kk + kc),
                (__attribute__((address_space(3))) void*)
                    (Bs + (size_t)(w * 64) * 8), 16, 0, 0);
        }
        __syncthreads();

        bf16x8 af[4], bf[NT];
#pragma unroll
        for (int mt = 0; mt < 4; mt++)
            af[mt] = *reinterpret_cast<const bf16x8*>(&As[(wm + mt * 16 + l15) * 32 + quad * 8]);
#pragma unroll
        for (int nt = 0; nt < NT; nt++)
            bf[nt] = *reinterpret_cast<const bf16x8*>(&Bs[(wn + nt * 16 + l15) * 32 + quad * 8]);
#pragma unroll
        for (int mt = 0; mt < 4; mt++)
#pragma unroll
            for (int nt = 0; nt < NT; nt++)
                acc[mt][nt] = __builtin_amdgcn_mfma_f32_16x16x32_bf16(
                    af[mt], bf[nt], acc[mt][nt], 0, 0, 0);
    }

#pragma unroll
    for (int mt = 0; mt < 4; mt++)
#pragma unroll
        for (int nt = 0; nt < NT; nt++) {
            const int n = n0 + wn + nt * 16 + l15;
            const float bv = bias[n];
#pragma unroll
            for (int r = 0; r < 4; r++) {
                const int m = m0 + wm + mt * 16 + quad * 4 + r;
                const float val = acc[mt][nt][r] + bv;
                if (MODE == 0) {
                    ushort_t* ws = (ushort_t*)out_;
                    const int which = n >> 10;         // 0:q 1:k 2:v
                    const int cc = n & 1023;
                    const int h = cc >> 6, d = cc & 63;
                    const int bb = m >> 10, t = m & 1023;
                    if (which == 2) {
                        ws[2 * PLANE + ((size_t)(bb * NHEAD + h) * HDIM + d) * T_SEQ + t] = f2bf(val);
                    } else {
                        const float sv = (which == 0) ? val * C1SCALE : val;
                        ws[(size_t)which * PLANE +
                           ((size_t)(bb * NHEAD + h) * T_SEQ + t) * HDIM + d] = f2bf(sv);
                    }
                } else {
                    ((float*)out_)[(size_t)m * Ndim + n] = val;
                }
            }
        }
}

// ---------------------------------------------------------------------------
// Flash attention w/ rel-pos band. Grid (64, 16): bh = bx, i-tile = 15 - by
// (heavy-first; natural %256 distribution balances CUs). 40KB LDS, 4/CU.
// Es = 2 parity halves of 64 rows (rotation: tile jt uses halves k=jt-1
// [slot (jt&1)^1, rows d0..d0+63] and k=jt [slot jt&1, rows d0-64..d0-1]);
// only half k=jt+1 is staged per tile (post-S3, latency hidden).
// P band TRANSPOSED: Ps[jl][il], phys col = il ^ ((jl&7)<<2) (bits 2-4 ->
// b64 gather alignment preserved). Gather = 4x ds_read_b64 per thread.
// Probs reuse Ks region after S3 (stripe-private rows, T2 XOR) as before.
// Barriers: S1 = lgkm-only (E prefetch stays in flight), S2 = full
// __syncthreads (drains staging vmcnt), S3 = __syncthreads.
// ---------------------------------------------------------------------------
__global__ __launch_bounds__(256) void flash_attn(
    const ushort_t* __restrict__ qp, const ushort_t* __restrict__ kp,
    const ushort_t* __restrict__ vTp, const ushort_t* __restrict__ E16,
    ushort_t* __restrict__ y16)
{
    __shared__ __align__(16) ushort_t Ks[64 * 64];    // K tile; probs after S3
    __shared__ __align__(16) ushort_t Vt[64 * 64];
    __shared__ __align__(16) ushort_t Es[128 * 64];   // 2 rotating 64-row halves
    __shared__ __align__(16) ushort_t Ps[64 * 64];    // transposed P band

    const int bh = blockIdx.x;
    const int h = bh & (NHEAD - 1);
    const int b = bh >> 4;
    const int it = 15 - (int)blockIdx.y;
    const int tid = threadIdx.x;
    const int w = tid >> 6;
    const int lane = tid & 63;
    const int l15 = lane & 15;
    const int quad = lane >> 4;

    const size_t base = (size_t)bh * T_SEQ * HDIM;
    const ushort_t* Eh = E16 + (size_t)h * T_SEQ * HDIM;
    const ushort_t* vTb = vTp + (size_t)bh * 65536;

    const int kswz = (l15 & 7) << 3;   // K/V/E read-side col XOR (16B granular)
    const int pswz = (l15 & 7) << 2;   // Ps col XOR (4-elem granular, b64-safe)

    // staging lane geometry (per 8-row global_load_lds call)
    const int srow = lane >> 3;        // row within 8-row block
    const int scc  = lane & 7;         // 16B chunk within 128B row

    bf16x8 ones;
#pragma unroll
    for (int i = 0; i < 8; i++) ones[i] = (__bf16)1.0f;

    const int i0 = it * 64;

    // stage E half k (absolute rows i0-(k+1)*64 .. i0-k*64-1) into slot k&1
    auto stage_e = [&](int k) {
        const int sk = k & 1;
#pragma unroll
        for (int t = 0; t < 2; t++) {
            const int r0 = w * 16 + t * 8;
            const int row = r0 + srow;
            int g = i0 - (k + 1) * 64 + row;
            g = g < 0 ? 0 : (g > 1023 ? 1023 : g);
            const int sx = (scc ^ (row & 7)) << 3;
            __builtin_amdgcn_global_load_lds(
                (const __attribute__((address_space(1))) void*)
                    (Eh + (size_t)g * HDIM + sx),
                (__attribute__((address_space(3))) void*)(&Es[(sk * 64 + r0) * 64]),
                16, 0, 0);
        }
    };

    // Q A-fragments straight from global (wave-private rows; pre-scaled c1)
    bf16x8 qf[2];
    {
        const ushort_t* qrow = qp + base + (size_t)(i0 + w * 16 + l15) * HDIM;
        qf[0] = *reinterpret_cast<const bf16x8*>(qrow + quad * 8);
        qf[1] = *reinterpret_cast<const bf16x8*>(qrow + 32 + quad * 8);
    }

    f32x4 o[4], o5;
#pragma unroll
    for (int dt = 0; dt < 4; dt++) o[dt] = (f32x4){0.f, 0.f, 0.f, 0.f};
    o5 = (f32x4){0.f, 0.f, 0.f, 0.f};

    // prologue: both E halves for tile 0 (k=-1 -> slot 1, k=0 -> slot 0)
    stage_e(-1);
    stage_e(0);

    for (int jt = 0; jt <= it; ++jt) {
        const int j0 = jt * 64;
        // S1: lgkm-only barrier (PV LDS reads drained; E prefetch vmem stays
        // in flight). R14-validated pattern + rule-18 sched fence.
        asm volatile("s_waitcnt lgkmcnt(0)" ::: "memory");
        __builtin_amdgcn_s_barrier();
        __builtin_amdgcn_sched_barrier(0);
        {   // stage K, V^T via global_load_lds (zero VGPR)
#pragma unroll
            for (int t = 0; t < 2; t++) {
                const int r0 = w * 16 + t * 8;
                const int row = r0 + srow;
                const int sx = (scc ^ (row & 7)) << 3;
                __builtin_amdgcn_global_load_lds(
                    (const __attribute__((address_space(1))) void*)
                        (kp + base + (size_t)(j0 + row) * HDIM + sx),
                    (__attribute__((address_space(3))) void*)(&Ks[r0 * 64]),
                    16, 0, 0);
                __builtin_amdgcn_global_load_lds(
                    (const __attribute__((address_space(1))) void*)
                        (vTb + (size_t)row * T_SEQ + j0 + sx),
                    (__attribute__((address_space(3))) void*)(&Vt[r0 * 64]),
                    16, 0, 0);
            }
        }
        __syncthreads();   // S2: all staging complete (drains vmcnt)

        // ---- phase 1: S = Q@K^T ; P band = E@K^T (pre-scaled c1) ----
        // Es slot per wave: rows re<64 (w=0,1) -> slot jt&1; re>=64 -> ^1.
        const int erow = (((jt & 1) ^ (w >> 1)) << 6) + (w & 1) * 32 + l15;
        f32x4 s[4], pb[2][4];
#pragma unroll
        for (int nt = 0; nt < 4; nt++) {
            s[nt] = (f32x4){0.f, 0.f, 0.f, 0.f};
            pb[0][nt] = (f32x4){0.f, 0.f, 0.f, 0.f};
            pb[1][nt] = (f32x4){0.f, 0.f, 0.f, 0.f};
        }
        __builtin_amdgcn_s_setprio(1);
#pragma unroll
        for (int ks = 0; ks < 2; ks++) {
            const int ko = ks * 32 + quad * 8;
            const bf16x8 ae0 = *reinterpret_cast<const bf16x8*>(&Es[erow * 64 + (ko ^ kswz)]);
            const bf16x8 ae1 = *reinterpret_cast<const bf16x8*>(&Es[(erow + 16) * 64 + (ko ^ kswz)]);
#pragma unroll
            for (int nt = 0; nt < 4; nt++) {
                const bf16x8 bk = *reinterpret_cast<const bf16x8*>(&Ks[(nt * 16 + l15) * 64 + (ko ^ kswz)]);
                s[nt] = __builtin_amdgcn_mfma_f32_16x16x32_bf16(qf[ks], bk, s[nt], 0, 0, 0);
                pb[0][nt] = __builtin_amdgcn_mfma_f32_16x16x32_bf16(ae0, bk, pb[0][nt], 0, 0, 0);
                pb[1][nt] = __builtin_amdgcn_mfma_f32_16x16x32_bf16(ae1, bk, pb[1][nt], 0, 0, 0);
            }
        }
        __builtin_amdgcn_s_setprio(0);
        // transposed skew store: Ps[jl][il] = P[il-jl+64][jl]; OOB lanes skip
#pragma unroll
        for (int mf = 0; mf < 2; mf++)
#pragma unroll
            for (int nt = 0; nt < 4; nt++) {
                const int jl = nt * 16 + l15;
#pragma unroll
                for (int r = 0; r < 4; r++) {
                    const int br = w * 32 + mf * 16 + quad * 4 + r;
                    const int il_t = br - 64 + jl;
                    if ((unsigned)il_t < 64u)
                        Ps[jl * 64 + (il_t ^ pswz)] = f2bf(pb[mf][nt][r]);
                }
            }
        __syncthreads();   // S3: skew store done; phase-1 Es/Ks reads drained

        // early-stage next tile's new E half (into the slot just freed)
        if (jt < it) stage_e(jt + 1);

        // ---- b64 gather + static-max softmax: P = exp2(sv - SMAX) ----
        float pv[4][4];
        const int il0 = w * 16 + quad * 4;   // == 0 mod 4 -> b64 aligned
        const bool diag = (j0 == i0);
#pragma unroll
        for (int nt = 0; nt < 4; nt++) {
            const int jl = nt * 16 + l15;
            const unsigned long long pw =
                *reinterpret_cast<const unsigned long long*>(&Ps[jl * 64 + (il0 ^ pswz)]);
            const unsigned w0 = (unsigned)pw, w1 = (unsigned)(pw >> 32);
            float p[4];
            { unsigned u = w0 << 16;         __builtin_memcpy(&p[0], &u, 4); }
            { unsigned u = w0 & 0xFFFF0000u; __builtin_memcpy(&p[1], &u, 4); }
            { unsigned u = w1 << 16;         __builtin_memcpy(&p[2], &u, 4); }
            { unsigned u = w1 & 0xFFFF0000u; __builtin_memcpy(&p[3], &u, 4); }
#pragma unroll
            for (int r = 0; r < 4; r++) {
                const float e = exp2f(s[nt][r] + p[r] - SMAX);
                pv[nt][r] = (diag && jl > il0 + r) ? 0.0f : e;
            }
        }
        // probs -> Ks region (free after S3; stripe-private rows w*16..w*16+15)
#pragma unroll
        for (int nt = 0; nt < 4; nt++)
#pragma unroll
            for (int r = 0; r < 4; r++) {
                const int rr = w * 16 + quad * 4 + r;
                Ks[rr * 64 + ((nt * 16 + l15) ^ ((rr & 7) << 3))] = f2bf(pv[nt][r]);
            }
        // (no barrier: PV reads below touch only this wave's stripe)

        // ---- O += P @ V ; denominator via ones column ----
        __builtin_amdgcn_s_setprio(1);
#pragma unroll
        for (int ks = 0; ks < 2; ks++) {
            const int ko = ks * 32 + quad * 8;
            const bf16x8 ap = *reinterpret_cast<const bf16x8*>(&Ks[(w * 16 + l15) * 64 + (ko ^ kswz)]);
#pragma unroll
            for (int dt = 0; dt < 4; dt++) {
                const bf16x8 bv = *reinterpret_cast<const bf16x8*>(&Vt[(dt * 16 + l15) * 64 + (ko ^ kswz)]);
                o[dt] = __builtin_amdgcn_mfma_f32_16x16x32_bf16(ap, bv, o[dt], 0, 0, 0);
            }
            o5 = __builtin_amdgcn_mfma_f32_16x16x32_bf16(ap, ones, o5, 0, 0, 0);
        }
        __builtin_amdgcn_s_setprio(0);
    }

    // ---- epilogue: y16[b][i][h*64+d] = O / l  (2^-SMAX scale cancels) ----
    float inv[4];
#pragma unroll
    for (int r = 0; r < 4; r++) inv[r] = 1.0f / o5[r];
#pragma unroll
    for (int dt = 0; dt < 4; dt++)
#pragma unroll
        for (int r = 0; r < 4; r++) {
            const int il = w * 16 + quad * 4 + r;
            const int d = dt * 16 + l15;
            y16[((size_t)(b * T_SEQ + i0 + il)) * 1024 + h * 64 + d] = f2bf(o[dt][r] * inv[r]);
        }
}

extern "C" void kernel_launch(void* const* d_in, const int* in_sizes, int n_in,
                              void* d_out, int out_size, void* d_ws, size_t ws_size,
                              hipStream_t stream) {
    float* out = (float*)d_out;

    const void* x = nullptr; const void* Wa = nullptr; const void* ba = nullptr;
    const void* Wp = nullptr; const void* bp = nullptr; const void* E = nullptr;
    int anomaly = 0;
    if (n_in != 6) {
        anomaly = 2;
    } else {
        int c1M = 0;
        for (int i = 0; i < 6; i++) {
            const int s = in_sizes[i];
            if      (s == 4194304) x  = d_in[i];
            else if (s == 3145728) Wa = d_in[i];
            else if (s == 3072)    ba = d_in[i];
            else if (s == 1024)    bp = d_in[i];
            else if (s == 1048576) { if (c1M == 0) Wp = d_in[i]; else E = d_in[i]; c1M++; }
            else anomaly = 1;
        }
        if (!x || !Wa || !ba || !Wp || !bp || !E || c1M != 2) anomaly = 1;
    }
    if (!anomaly && out_size != 4194304) anomaly = 3;
    if (!anomaly && ws_size < (size_t)52428800) anomaly = 4;   // 50 MiB
    if (anomaly) {
        sentinel_kernel<<<(out_size + 255) / 256, 256, 0, stream>>>(out, out_size, 1000.0f * anomaly);
        return;
    }

    ushort_t* ws   = (ushort_t*)d_ws;
    ushort_t* qp   = ws;                        // (B,H,T,HD) scaled by c1
    ushort_t* kp   = ws + (size_t)PLANE;        // (B,H,T,HD)
    ushort_t* vTp  = ws + (size_t)2 * PLANE;    // (B,H,HD,T) direct from gemm
    ushort_t* y16  = ws + (size_t)3 * PLANE;    // (B,T,C)
    ushort_t* x16  = ws + (size_t)4 * PLANE;
    ushort_t* WaT  = ws + (size_t)5 * PLANE;
    ushort_t* WpT  = WaT + (size_t)3145728;
    ushort_t* E16  = WpT + (size_t)1048576;     // scaled by c1

    // fused converts + weight transposes
    prep<<<6144, 256, 0, stream>>>((const float*)x, x16, (const float*)E, E16,
                                   (const float*)Wa, WaT, (const float*)Wp, WpT);

    // qkv: M=4096, N=3072, K=1024 -> q (scaled) / k / vT planes
    gemm128<0, 128><<<dim3(24, 32), 256, 0, stream>>>(x16, WaT, (const float*)ba, (void*)ws, 3072, 1024);

    // grid (64 bh, 16 i-tiles); heavy i-tiles (it=15) dispatch first
    flash_attn<<<dim3(64, 16), 256, 0, stream>>>(qp, kp, vTp, E16, y16);

    // proj: M=4096, N=1024, K=1024 -> fp32 out (128x64 tiles, 512 blocks)
    gemm128<1, 64><<<dim3(16, 32), 256, 0, stream>>>(y16, WpT, (const float*)bp, (void*)out, 1024, 1024);
}